// Round 3
// baseline (772.569 us; speedup 1.0000x reference)
//
#include <hip/hip_runtime.h>
#include <hip/hip_bf16.h>

typedef short bf16x8 __attribute__((ext_vector_type(8)));
typedef float f32x4 __attribute__((ext_vector_type(4)));
typedef int int4v __attribute__((ext_vector_type(4)));

#define OMEGA 30.0f

// ---------------- prep: transpose xi [B,C,H,W] f32 -> xt [B,HW,C] bf16 ----------------
__global__ __launch_bounds__(256) void k_transpose(const float* __restrict__ xi,
                                                   __hip_bfloat16* __restrict__ xt) {
  __shared__ float tile[32][33];
  int hw0 = blockIdx.x * 32, c0 = blockIdx.y * 32, b = blockIdx.z;
  int t = threadIdx.x;
  int r = t >> 5, cc = t & 31;
  const float* src = xi + (((size_t)b * 128 + c0) << 14) + hw0;
#pragma unroll
  for (int i = 0; i < 4; ++i)
    tile[r + i * 8][cc] = src[(size_t)(r + i * 8) * 16384 + cc];
  __syncthreads();
  __hip_bfloat16* dst = xt + (((size_t)b * 16384 + hw0) << 7) + c0;
#pragma unroll
  for (int i = 0; i < 4; ++i)
    dst[(size_t)(r + i * 8) * 128 + cc] = __float2bfloat16(tile[cc][r + i * 8]);
}

// ---------------- prep: W0 rows 0..3199 -> wt2[f][n][c] = W0[c*25+f][n] ----------------
// grid (25, 8): f, n-block of 32
__global__ __launch_bounds__(256) void k_prepw0(const float* __restrict__ W0,
                                                __hip_bfloat16* __restrict__ wt2) {
  __shared__ float tile[128][33];
  int f = blockIdx.x, nb = blockIdx.y;
  int t = threadIdx.x;
  int nn = t & 31, cr = t >> 5;  // cr 0..7
#pragma unroll
  for (int i = 0; i < 16; ++i) {
    int c = cr * 16 + i;
    tile[c][nn] = W0[(size_t)(c * 25 + f) * 256 + nb * 32 + nn];
  }
  __syncthreads();
#pragma unroll
  for (int i = 0; i < 16; ++i) {
    int idx = i * 256 + t;
    int n = idx >> 7, c = idx & 127;
    wt2[(size_t)f * 32768 + (size_t)(nb * 32 + n) * 128 + c] = __float2bfloat16(tile[c][n]);
  }
}

// ---------------- prep: w1t[n][k] = W1[k][n], w2t likewise; grid (8,8,2) ----------------
__global__ __launch_bounds__(256) void k_prepw12(const float* __restrict__ W1,
                                                 const float* __restrict__ W2,
                                                 __hip_bfloat16* __restrict__ w1t,
                                                 __hip_bfloat16* __restrict__ w2t) {
  __shared__ float tile[32][33];
  const float* src = blockIdx.z ? W2 : W1;
  __hip_bfloat16* dst = blockIdx.z ? w2t : w1t;
  int k0 = blockIdx.x * 32, n0 = blockIdx.y * 32;
  int t = threadIdx.x;
  int r = t >> 5, cc = t & 31;
#pragma unroll
  for (int i = 0; i < 4; ++i)
    tile[r + i * 8][cc] = src[(size_t)(k0 + r + i * 8) * 256 + n0 + cc];
  __syncthreads();
#pragma unroll
  for (int i = 0; i < 4; ++i)
    dst[(size_t)(n0 + r + i * 8) * 256 + k0 + cc] = __float2bfloat16(tile[cc][r + i * 8]);
}

// ---------------- conv 5x5 (128->256) + coords + bias + sin ----------------
// grid (128, 4), block 256 (4 waves). Static LDS 59392 B -> 2 blocks/CU.
// K=3200 split as 50 tap-halves (25 taps x 2 channel-halves of 64).
__global__ __launch_bounds__(256) void k_conv(const __hip_bfloat16* __restrict__ xt,
                                              const __hip_bfloat16* __restrict__ wt2,
                                              const float* __restrict__ W0,
                                              const float* __restrict__ b0,
                                              __hip_bfloat16* __restrict__ h0) {
  __shared__ __align__(16) char Al[400 * 128];  // [pos 20x20][64ch], swz: slot^(pos&7)
  __shared__ __align__(16) char Bl[64 * 128];   // [n][64ch],        swz: slot^(n&7)
  int tid = threadIdx.x;
  int bx = blockIdx.x;
  int b = bx >> 6, tr = (bx >> 3) & 7, tc = bx & 7;
  int n0 = blockIdx.y << 6;
  int lane = tid & 63, wave = tid >> 6;
  int lr = lane & 15, lg = lane >> 4;

  f32x4 acc[4][4] = {};

  // prefetch B(t=0): f=0, cb=0
  int4v breg[2];
#pragma unroll
  for (int j = 0; j < 2; ++j) {
    int idx = j * 256 + tid;
    int n = idx >> 3, s = idx & 7;
    breg[j] = *(const int4v*)(wt2 + (size_t)(n0 + n) * 128 + s * 8);
  }

  for (int t = 0; t < 50; ++t) {
    int cb = (t >= 25) ? 1 : 0;
    int f = t - cb * 25;
    if (f == 0) {
      __syncthreads();  // previous halo readers done
      for (int idx = tid; idx < 3200; idx += 256) {
        int pos = idx >> 3, s = idx & 7;
        int py = pos / 20, px = pos - py * 20;
        int gh = (tr << 4) + py - 2, gw = (tc << 4) + px - 2;
        int4v v = {0, 0, 0, 0};
        if ((unsigned)gh < 128u && (unsigned)gw < 128u)
          v = *(const int4v*)(xt + (((size_t)((b << 14) + (gh << 7) + gw)) << 7) + cb * 64 + s * 8);
        *(int4v*)(Al + pos * 128 + ((s ^ (pos & 7)) << 4)) = v;
      }
    }
    __syncthreads();  // readers of B(t-1) done
#pragma unroll
    for (int j = 0; j < 2; ++j) {
      int idx = j * 256 + tid;
      int n = idx >> 3, s = idx & 7;
      *(int4v*)(Bl + n * 128 + ((s ^ (n & 7)) << 4)) = breg[j];
    }
    if (t < 49) {  // prefetch B(t+1) -> regs; latency hides under MFMA below
      int t2 = t + 1;
      int cb2 = (t2 >= 25) ? 1 : 0;
      int f2 = t2 - cb2 * 25;
#pragma unroll
      for (int j = 0; j < 2; ++j) {
        int idx = j * 256 + tid;
        int n = idx >> 3, s = idx & 7;
        breg[j] = *(const int4v*)(wt2 + (size_t)(f2 * 256 + n0 + n) * 128 + cb2 * 64 + s * 8);
      }
    }
    __syncthreads();  // halo + B(t) visible
    int fy = f / 5, fx = f - fy * 5;
    int px = lr + fx;
#pragma unroll
    for (int ks = 0; ks < 2; ++ks) {
      int sk = (ks << 2) + lg;  // 0..7
      bf16x8 a[4], bw[4];
#pragma unroll
      for (int mi = 0; mi < 4; ++mi) {
        int pos = ((wave << 2) + mi + fy) * 20 + px;
        a[mi] = *(const bf16x8*)(Al + pos * 128 + ((sk ^ (pos & 7)) << 4));
      }
#pragma unroll
      for (int ni = 0; ni < 4; ++ni) {
        int nr = (ni << 4) + lr;
        bw[ni] = *(const bf16x8*)(Bl + nr * 128 + ((sk ^ (nr & 7)) << 4));
      }
#pragma unroll
      for (int mi = 0; mi < 4; ++mi)
#pragma unroll
        for (int ni = 0; ni < 4; ++ni)
          acc[mi][ni] = __builtin_amdgcn_mfma_f32_16x16x32_bf16(a[mi], bw[ni], acc[mi][ni], 0, 0, 0);
    }
  }

  // epilogue: + b0 + gx*W0[3200] + gy*W0[3201], sin(30*z), store bf16
  float wA[4], wB[4], bb[4];
#pragma unroll
  for (int ni = 0; ni < 4; ++ni) {
    int n = n0 + (ni << 4) + lr;
    wA[ni] = W0[3200 * 256 + n];
    wB[ni] = W0[3201 * 256 + n];
    bb[ni] = b0[n];
  }
#pragma unroll
  for (int mi = 0; mi < 4; ++mi) {
    int pr = (wave << 2) + mi;
    int h = (tr << 4) + pr;
    float gy = -1.f + (2.f / 127.f) * (float)h;
#pragma unroll
    for (int j = 0; j < 4; ++j) {
      int pc = (lg << 2) + j;
      int w = (tc << 4) + pc;
      float gx = -1.f + (2.f / 127.f) * (float)w;
      size_t m = (size_t)((b << 14) + (h << 7) + w);
#pragma unroll
      for (int ni = 0; ni < 4; ++ni) {
        int n = n0 + (ni << 4) + lr;
        float v = acc[mi][ni][j] + bb[ni] + gx * wA[ni] + gy * wB[ni];
        h0[m * 256 + n] = __float2bfloat16(sinf(OMEGA * v));
      }
    }
  }
}

// ---------------- hidden layer: h_out = sin(30*(h_in @ W + b)) ----------------
// grid (256, 2), block 256 (4 waves 2x2). Static LDS 65536 B.
__global__ __launch_bounds__(256) void k_layer(const __hip_bfloat16* __restrict__ hin,
                                               const __hip_bfloat16* __restrict__ wt,
                                               const float* __restrict__ bias,
                                               __hip_bfloat16* __restrict__ hout) {
  __shared__ __align__(16) char Al[128 * 256];  // [m][128ch half], swz: s^(r&15)
  __shared__ __align__(16) char Bl[128 * 256];  // [n][128ch half]
  int tid = threadIdx.x;
  int m0 = blockIdx.x << 7, n0 = blockIdx.y << 7;
  int lane = tid & 63, wave = tid >> 6;
  int lr = lane & 15, lg = lane >> 4;
  int wm = (wave >> 1) << 6, wn = (wave & 1) << 6;
  f32x4 acc[4][4] = {};

  for (int cb = 0; cb < 2; ++cb) {
    if (cb) __syncthreads();  // phase-0 readers done
#pragma unroll
    for (int i = 0; i < 8; ++i) {
      int idx = i * 256 + tid;  // 0..2047
      int r = idx >> 4, s = idx & 15;
      *(int4v*)(Al + r * 256 + ((s ^ (r & 15)) << 4)) =
          *(const int4v*)(hin + (size_t)(m0 + r) * 256 + cb * 128 + s * 8);
      *(int4v*)(Bl + r * 256 + ((s ^ (r & 15)) << 4)) =
          *(const int4v*)(wt + (size_t)(n0 + r) * 256 + cb * 128 + s * 8);
    }
    __syncthreads();
#pragma unroll
    for (int ks = 0; ks < 4; ++ks) {
      int sk = (ks << 2) + lg;  // 0..15
      bf16x8 a[4], bw[4];
#pragma unroll
      for (int mi = 0; mi < 4; ++mi) {
        int r = wm + (mi << 4) + lr;
        a[mi] = *(const bf16x8*)(Al + r * 256 + ((sk ^ (r & 15)) << 4));
      }
#pragma unroll
      for (int ni = 0; ni < 4; ++ni) {
        int r = wn + (ni << 4) + lr;
        bw[ni] = *(const bf16x8*)(Bl + r * 256 + ((sk ^ (r & 15)) << 4));
      }
#pragma unroll
      for (int mi = 0; mi < 4; ++mi)
#pragma unroll
        for (int ni = 0; ni < 4; ++ni)
          acc[mi][ni] = __builtin_amdgcn_mfma_f32_16x16x32_bf16(a[mi], bw[ni], acc[mi][ni], 0, 0, 0);
    }
  }

  float bb[4];
#pragma unroll
  for (int ni = 0; ni < 4; ++ni) bb[ni] = bias[n0 + wn + (ni << 4) + lr];
#pragma unroll
  for (int mi = 0; mi < 4; ++mi)
#pragma unroll
    for (int j = 0; j < 4; ++j) {
      size_t m = (size_t)(m0 + wm + (mi << 4) + (lg << 2) + j);
#pragma unroll
      for (int ni = 0; ni < 4; ++ni) {
        int n = n0 + wn + (ni << 4) + lr;
        hout[(m << 8) + n] = __float2bfloat16(sinf(OMEGA * (acc[mi][ni][j] + bb[ni])));
      }
    }
}

// ---------------- head: out[b][o][h][w] = h2 @ W3 + b3 ----------------
__global__ __launch_bounds__(256) void k_head(const __hip_bfloat16* __restrict__ h2,
                                              const float* __restrict__ W3,
                                              const float* __restrict__ b3,
                                              float* __restrict__ out) {
  __shared__ __align__(16) __hip_bfloat16 hl[64 * 256];
  __shared__ float w3l[768];
  int tid = threadIdx.x;
  int m0 = blockIdx.x << 6;
#pragma unroll
  for (int i = 0; i < 8; ++i) {
    int idx = i * 256 + tid;
    *(int4v*)((char*)hl + idx * 16) = *(const int4v*)(h2 + ((size_t)m0 << 8) + idx * 8);
  }
  for (int i = tid; i < 768; i += 256) w3l[i] = W3[i];
  __syncthreads();
  int pix = tid >> 2, o = tid & 3;
  if (o < 3) {
    float acc = b3[o];
    for (int c0 = 0; c0 < 32; ++c0) {
      int c = (c0 + pix) & 31;
      bf16x8 v = *(const bf16x8*)((char*)hl + pix * 512 + c * 16);
#pragma unroll
      for (int j = 0; j < 8; ++j) {
        unsigned short u = (unsigned short)v[j];
        float hv = __uint_as_float((unsigned)u << 16);
        acc += hv * w3l[(c * 8 + j) * 3 + o];
      }
    }
    int m = m0 + pix;
    int b = m >> 14, hw = m & 16383;
    out[((b * 3 + o) << 14) + hw] = acc;
  }
}

extern "C" void kernel_launch(void* const* d_in, const int* in_sizes, int n_in,
                              void* d_out, int out_size, void* d_ws, size_t ws_size,
                              hipStream_t stream) {
  const float* xi = (const float*)d_in[0];
  const float* W0 = (const float*)d_in[1];
  const float* b0 = (const float*)d_in[2];
  const float* W1 = (const float*)d_in[3];
  const float* b1 = (const float*)d_in[4];
  const float* W2 = (const float*)d_in[5];
  const float* b2 = (const float*)d_in[6];
  const float* W3 = (const float*)d_in[7];
  const float* b3 = (const float*)d_in[8];
  float* out = (float*)d_out;
  char* ws = (char*)d_ws;

  __hip_bfloat16* xt  = (__hip_bfloat16*)(ws + 0);          //  8,388,608 B
  __hip_bfloat16* wt2 = (__hip_bfloat16*)(ws + 8388608);    //  1,638,400 B
  __hip_bfloat16* w1t = (__hip_bfloat16*)(ws + 10027008);   //    131,072 B
  __hip_bfloat16* w2t = (__hip_bfloat16*)(ws + 10158080);   //    131,072 B
  __hip_bfloat16* h0  = (__hip_bfloat16*)(ws + 10289152);   // 16,777,216 B (reused as h2)
  __hip_bfloat16* h1  = (__hip_bfloat16*)(ws + 27066368);   // 16,777,216 B

  k_transpose<<<dim3(512, 4, 2), 256, 0, stream>>>(xi, xt);
  k_prepw0<<<dim3(25, 8), 256, 0, stream>>>(W0, wt2);
  k_prepw12<<<dim3(8, 8, 2), 256, 0, stream>>>(W1, W2, w1t, w2t);
  k_conv<<<dim3(128, 4), 256, 0, stream>>>(xt, wt2, W0, b0, h0);
  k_layer<<<dim3(256, 2), 256, 0, stream>>>(h0, w1t, b1, h1);
  k_layer<<<dim3(256, 2), 256, 0, stream>>>(h1, w2t, b2, h0);
  k_head<<<512, 256, 0, stream>>>(h0, W3, b3, out);
}